// Round 1
// baseline (187.699 us; speedup 1.0000x reference)
//
#include <hip/hip_runtime.h>
#include <math.h>

#define BB 64
#define LL 512
#define SS 512
#define HH 768
#define CC 9
#define WPB 32                    // words per block
#define GF (BB * SS / WPB)        // 1024 fused blocks
#define NPART (GF * 4)            // per-wave partials (4096)

// DPP full-wave (64-lane) sum; total lands in lane 63. Pure VALU, no LDS.
template <int CTRL>
__device__ __forceinline__ float dpp_add(float x) {
    int y = __builtin_amdgcn_update_dpp(0, __float_as_int(x), CTRL, 0xf, 0xf, true);
    return x + __int_as_float(y);
}
__device__ __forceinline__ float rsum64(float x) {
    x = dpp_add<0x111>(x);  // row_shr:1
    x = dpp_add<0x112>(x);  // row_shr:2
    x = dpp_add<0x114>(x);  // row_shr:4
    x = dpp_add<0x118>(x);  // row_shr:8
    x = dpp_add<0x142>(x);  // row_bcast:15
    x = dpp_add<0x143>(x);  // row_bcast:31 -> lane 63 = full sum
    return x;
}

// Kernel 0: W[H][C] -> WT[C][H] in ws (27 KB, L2-resident after)
__global__ __launch_bounds__(256) void wt_kernel(const float* __restrict__ Wm,
                                                 float* __restrict__ WT_g) {
    int e = blockIdx.x * 256 + threadIdx.x;
    if (e < HH * CC) {
        int h = e / CC;
        int c = e - h * CC;
        WT_g[c * HH + h] = Wm[e];
    }
}

// Kernel 1 (fused): mean-pool is linear, so pool rows in H-space while
// streaming bert exactly once, then one 9-class dot + softmax PER WORD.
// Block = one batch x 32 consecutive words; wave = 8 consecutive words
// (their subword rows are contiguous -> coalesced stream + 1-row prefetch).
__global__ __launch_bounds__(256) void fused_kernel(
    const float* __restrict__ bert,      // [B*L, H]
    const float* __restrict__ WT_g,      // [C][H]
    const float* __restrict__ bias,      // [C]
    const int* __restrict__ ids_lens,    // [B, S]
    const int* __restrict__ label_ids,   // [B, S]
    float* __restrict__ pred_out,        // d_out + 1
    float* __restrict__ nll_part,        // [NPART]
    float* __restrict__ cnt_part)        // [NPART]
{
    __shared__ int wlen[WPB];
    __shared__ int woff[WPB + 1];
    __shared__ float red[4];
    __shared__ int s_start_sh;

    int b = blockIdx.x >> 4;             // batch (16 blocks per batch)
    int chunk = blockIdx.x & 15;
    int w0 = chunk * WPB;                // first word of this block
    const int* lens = ids_lens + b * SS;
    int t = threadIdx.x, lane = t & 63, wave = t >> 6;

    if (t < WPB) wlen[t] = lens[w0 + t];

    // sum of lens[0..w0) -> first subword row of this block (ints < 1536: exact)
    int part = 0;
    for (int i = t; i < w0; i += 256) part += lens[i];
    float pf = rsum64((float)part);
    if (lane == 63) red[wave] = pf;
    __syncthreads();
    if (t == 0) {
        int run = 0;
#pragma unroll
        for (int k = 0; k < WPB; k++) { woff[k] = run; run += wlen[k]; }
        woff[WPB] = run;
        s_start_sh = (int)(red[0] + red[1] + red[2] + red[3]);
    }
    __syncthreads();

    // lane's W slice: 27 float4, coalesced from L2-hot WT
    int hoff = lane * 4;
    float4 wreg[CC][3];
#pragma unroll
    for (int c = 0; c < CC; c++)
#pragma unroll
        for (int c3 = 0; c3 < 3; c3++)
            wreg[c][c3] = *reinterpret_cast<const float4*>(WT_g + c * HH + c3 * 256 + hoff);

    float bs[CC];
#pragma unroll
    for (int c = 0; c < CC; c++) bs[c] = bias[c];

    int w8 = wave * 8;                         // wave's first word (in block)
    int row0 = s_start_sh + woff[w8];          // wave's first subword row
    int nrows = woff[w8 + 8] - woff[w8];       // wave's contiguous row count
    const float* p = bert + ((size_t)b * LL + row0) * HH + hoff;

    // 1-row register prefetch (guarded: never reads past the wave's range)
    float4 n0, n1, n2;
    n0.x = n0.y = n0.z = n0.w = 0.0f; n1 = n0; n2 = n0;
    if (nrows > 0) {
        n0 = *reinterpret_cast<const float4*>(p);
        n1 = *reinterpret_cast<const float4*>(p + 256);
        n2 = *reinterpret_cast<const float4*>(p + 512);
    }
    int j = 0;
    float nll_acc = 0.0f, cnt_acc = 0.0f;      // lane 63 carries these

    for (int k = 0; k < 8; ++k) {
        int len = wlen[w8 + k];                // wave-uniform (LDS broadcast)
        float acc[CC];
#pragma unroll
        for (int c = 0; c < CC; c++) acc[c] = 0.0f;

        for (int jj = 0; jj < len; ++jj) {
#pragma unroll
            for (int c = 0; c < CC; c++) {
                acc[c] += n0.x * wreg[c][0].x + n0.y * wreg[c][0].y
                        + n0.z * wreg[c][0].z + n0.w * wreg[c][0].w
                        + n1.x * wreg[c][1].x + n1.y * wreg[c][1].y
                        + n1.z * wreg[c][1].z + n1.w * wreg[c][1].w
                        + n2.x * wreg[c][2].x + n2.y * wreg[c][2].y
                        + n2.z * wreg[c][2].z + n2.w * wreg[c][2].w;
            }
            ++j;
            if (j < nrows) {                   // wave-uniform guard
                const float* q = p + (size_t)j * HH;
                n0 = *reinterpret_cast<const float4*>(q);
                n1 = *reinterpret_cast<const float4*>(q + 256);
                n2 = *reinterpret_cast<const float4*>(q + 512);
            }
        }

        // one 64-lane reduce PER WORD (was per subword row)
#pragma unroll
        for (int c = 0; c < CC; c++) acc[c] = rsum64(acc[c]);

        if (lane == 63) {
            float inv = 1.0f / (float)(len > 0 ? len : 1);
            float lg[CC];
#pragma unroll
            for (int c = 0; c < CC; c++) lg[c] = acc[c] * inv + bs[c];

            float mx = lg[0];
            int arg = 0;
#pragma unroll
            for (int c = 1; c < CC; c++) {
                if (lg[c] > mx) { mx = lg[c]; arg = c; }
            }
            float se = 0.0f;
#pragma unroll
            for (int c = 0; c < CC; c++) se += expf(lg[c] - mx);
            float lse = mx + logf(se);

            int g = b * SS + w0 + w8 + k;
            int lab = label_ids[g];
            lab = lab < 0 ? 0 : (lab > CC - 1 ? CC - 1 : lab);
            float valid = (len > 0) ? 1.0f : 0.0f;
            pred_out[g] = (float)arg;
            nll_acc += (lse - lg[lab]) * valid;
            cnt_acc += valid;
        }
    }

    if (lane == 63) {
        int pid = blockIdx.x * 4 + wave;
        nll_part[pid] = nll_acc;
        cnt_part[pid] = cnt_acc;
    }
}

// Kernel 2: deterministic reduction of 4096 per-wave partials -> loss
__global__ __launch_bounds__(1024) void finalize_kernel(
    const float* __restrict__ nll_part,
    const float* __restrict__ cnt_part,
    float* __restrict__ out_loss) {
    __shared__ float sn[16], sc[16];
    int t = threadIdx.x, lane = t & 63, wave = t >> 6;
    float n = 0.0f, c = 0.0f;
#pragma unroll
    for (int i = 0; i < NPART / 1024; ++i) {
        n += nll_part[t + i * 1024];
        c += cnt_part[t + i * 1024];
    }
    n = rsum64(n);
    c = rsum64(c);
    if (lane == 63) { sn[wave] = n; sc[wave] = c; }
    __syncthreads();
    if (t == 0) {
        float tn = 0.0f, tc = 0.0f;
#pragma unroll
        for (int i = 0; i < 16; i++) { tn += sn[i]; tc += sc[i]; }
        out_loss[0] = tn / fmaxf(tc, 1.0f);
    }
}

extern "C" void kernel_launch(void* const* d_in, const int* in_sizes, int n_in,
                              void* d_out, int out_size, void* d_ws, size_t ws_size,
                              hipStream_t stream) {
    const float* bert = (const float*)d_in[0]; // float32 [B,L,H]
    const float* Wm   = (const float*)d_in[1]; // float32 [H,C]
    const float* bias = (const float*)d_in[2]; // float32 [C]
    // d_in[3] = attention_mask (unused: prefix mask implied by ids_lens)
    const int* ids_lens  = (const int*)d_in[4];
    const int* label_ids = (const int*)d_in[5];
    // d_in[6] = label_mask (derived from ids_lens > 0)

    float* out = (float*)d_out;  // [0]=loss, [1..32768]=pred, float32

    float* WT_g     = (float*)d_ws;            // [C][H]  27648 B
    float* nll_part = WT_g + CC * HH;          // [NPART]
    float* cnt_part = nll_part + NPART;        // [NPART]

    wt_kernel<<<(HH * CC + 255) / 256, 256, 0, stream>>>(Wm, WT_g);
    fused_kernel<<<GF, 256, 0, stream>>>(bert, WT_g, bias, ids_lens, label_ids,
                                         out + 1, nll_part, cnt_part);
    finalize_kernel<<<1, 1024, 0, stream>>>(nll_part, cnt_part, out);
}